// Round 3
// baseline (109.660 us; speedup 1.0000x reference)
//
#include <hip/hip_runtime.h>

#define NB 8
#define LQ 4096
#define SK 4096
#define NH 8
#define DD 64
#define NPAIR (NB*NH)        // 64 (n,h) pairs
#define KVSZ (DD*DD + DD)    // 4160: 64x64 KV + 64 Ksum

__device__ __forceinline__ float fmap(float x) {
    // elu(x)+1 : x>0 ? x+1 : exp(x)
    return x > 0.f ? x + 1.f : __expf(x);
}

// ---------------- Phase 1: partial KV = sum_s K[s]⊗V[s], Ksum = sum_s K[s] --------
// 128 threads (2 waves), 32-row s-tiles (17KB LDS -> up to 9 blocks/CU), each
// thread owns a 4(d)x8(v) patch: per s-row 3 ds_read_b128 feed 32 FMAs.
__global__ __launch_bounds__(128, 4) void kv_partial_kernel(
    const float* __restrict__ K, const float* __restrict__ V,
    const float* __restrict__ kvm, float* __restrict__ partial,
    int CH, int SC)
{
    int bx = blockIdx.x;
    int chunk = bx % CH;
    int pair  = bx / CH;
    int n = pair >> 3, h = pair & 7;
    int t = threadIdx.x;
    int dg = t >> 3;      // 0..15 -> d rows dg*4..dg*4+3 (wave: 8 distinct addrs, conflict-free)
    int vg = t & 7;       // 0..7  -> v cols vg*8..vg*8+7 (2-way, free)
    int col = t & 63, half = t >> 6;

    __shared__ float Kl[32][64];
    __shared__ float Vl[32][64];
    __shared__ float Ks[2][64];

    float acc[4][8] = {};
    float ksum = 0.f;

    int s0 = chunk * SC;
    for (int s = s0; s < s0 + SC; s += 32) {
        // stage 32x64 K,V (2048 floats each = 4 float4 per thread), coalesced
#pragma unroll
        for (int k = 0; k < 4; ++k) {
            int f = t + 128 * k;
            int r = f >> 4, c = f & 15;
            size_t base = ((size_t)((n * SK + s + r) * NH + h)) * DD + c * 4;
            float m = kvm[n * SK + s + r];
            float4 kf = *(const float4*)(K + base);
            float4 vf = *(const float4*)(V + base);
            kf.x = fmap(kf.x) * m; kf.y = fmap(kf.y) * m;
            kf.z = fmap(kf.z) * m; kf.w = fmap(kf.w) * m;
            vf.x *= m; vf.y *= m; vf.z *= m; vf.w *= m;
            *(float4*)&Kl[r][c * 4] = kf;
            *(float4*)&Vl[r][c * 4] = vf;
        }
        __syncthreads();

        // ksum: wave `half` sums rows half*16..+15 of column `col` (2-way, free)
#pragma unroll
        for (int i = 0; i < 16; ++i) ksum += Kl[half * 16 + i][col];

        // rank-1 accumulation: 3 b128 reads -> 32 FMA
#pragma unroll 8
        for (int r = 0; r < 32; ++r) {
            float4 kf = *(const float4*)&Kl[r][dg * 4];
            float4 v0 = *(const float4*)&Vl[r][vg * 8];
            float4 v1 = *(const float4*)&Vl[r][vg * 8 + 4];
#pragma unroll
            for (int i = 0; i < 4; ++i) {
                float kd = (i == 0) ? kf.x : (i == 1) ? kf.y : (i == 2) ? kf.z : kf.w;
                acc[i][0] += kd * v0.x; acc[i][1] += kd * v0.y;
                acc[i][2] += kd * v0.z; acc[i][3] += kd * v0.w;
                acc[i][4] += kd * v1.x; acc[i][5] += kd * v1.y;
                acc[i][6] += kd * v1.z; acc[i][7] += kd * v1.w;
            }
        }
        __syncthreads();
    }

    float* dst = partial + ((size_t)chunk * NPAIR + pair) * KVSZ;
#pragma unroll
    for (int i = 0; i < 4; ++i) {
        *(float4*)&dst[(dg * 4 + i) * 64 + vg * 8] =
            make_float4(acc[i][0], acc[i][1], acc[i][2], acc[i][3]);
        *(float4*)&dst[(dg * 4 + i) * 64 + vg * 8 + 4] =
            make_float4(acc[i][4], acc[i][5], acc[i][6], acc[i][7]);
    }
    Ks[half][col] = ksum;
    __syncthreads();
    if (t < 64) dst[4096 + t] = Ks[0][t] + Ks[1][t];
}

// ---------------- Phase 1b: reduce partials over chunks -----------------
__global__ __launch_bounds__(256) void kv_reduce_kernel(
    const float* __restrict__ partial, float* __restrict__ kvf, int CH)
{
    int i = blockIdx.x * 256 + threadIdx.x;
    if (i >= NPAIR * KVSZ) return;
    float s = 0.f;
    for (int c = 0; c < CH; ++c) s += partial[(size_t)c * NPAIR * KVSZ + i];
    kvf[i] = s;
}

// ---------------- Phase 2: out = (q·KV) / (q·Ksum + eps) -----------------
// 128 threads, 64 Q-rows/block. Only transposed Q in LDS (17.4KB -> 9
// blocks/CU); KV + Ksum read from global (L1/L2-resident, shared by the 64
// blocks of a pair; Ksum is wave-uniform -> scalar load). Per-thread 4r x 8c:
// per d-iter 1 ds_read_b128 + 2 global b128 + 36 FMA.
__global__ __launch_bounds__(128, 4) void attn_out_kernel(
    const float* __restrict__ Q, const float* __restrict__ qm,
    const float* __restrict__ kvf, float* __restrict__ out)
{
    int bx = blockIdx.x;
    int tile = bx & 63;          // consecutive blocks share a pair (L2 locality)
    int pair = bx >> 6;
    int n = pair >> 3, h = pair & 7;
    int t = threadIdx.x;
    int rg = t >> 3;             // rows rg*4..rg*4+3
    int cg = t & 7;              // cols cg*8..cg*8+7

    __shared__ float Qt[64][68]; // transposed, pad 68 (17 float4) -> aligned + conflict-free reads

    const float* kvp = kvf + (size_t)pair * KVSZ;
    int l0 = tile * 64;

    // stage Q transposed: 4096 floats = 8 float4 per thread, coalesced loads
#pragma unroll
    for (int k = 0; k < 8; ++k) {
        int f = t + 128 * k;
        int r = f >> 4, c = f & 15;      // d0 = c*4
        float m = qm[n * LQ + l0 + r];
        float4 qf = *(const float4*)(Q + ((size_t)((n * LQ + l0 + r) * NH + h)) * DD + c * 4);
        Qt[c * 4 + 0][r] = fmap(qf.x) * m;
        Qt[c * 4 + 1][r] = fmap(qf.y) * m;
        Qt[c * 4 + 2][r] = fmap(qf.z) * m;
        Qt[c * 4 + 3][r] = fmap(qf.w) * m;
    }
    __syncthreads();

    float acc[4][8] = {};
    float den[4] = {};

#pragma unroll 4
    for (int d = 0; d < 64; ++d) {
        float4 qv = *(const float4*)&Qt[d][rg * 4];           // 8 distinct addrs, all 32 banks
        float4 k0 = *(const float4*)(kvp + d * 64 + cg * 8);  // global, L1/L2-hit
        float4 k1 = *(const float4*)(kvp + d * 64 + cg * 8 + 4);
        float ks = kvp[4096 + d];                             // wave-uniform -> s_load
        den[0] += qv.x * ks; den[1] += qv.y * ks;
        den[2] += qv.z * ks; den[3] += qv.w * ks;
#pragma unroll
        for (int i = 0; i < 4; ++i) {
            float qd = (i == 0) ? qv.x : (i == 1) ? qv.y : (i == 2) ? qv.z : qv.w;
            acc[i][0] += qd * k0.x; acc[i][1] += qd * k0.y;
            acc[i][2] += qd * k0.z; acc[i][3] += qd * k0.w;
            acc[i][4] += qd * k1.x; acc[i][5] += qd * k1.y;
            acc[i][6] += qd * k1.z; acc[i][7] += qd * k1.w;
        }
    }

#pragma unroll
    for (int i = 0; i < 4; ++i) {
        float z = 1.f / (den[i] + 1e-6f);
        float* orow = out + ((size_t)((n * LQ + l0 + rg * 4 + i) * NH + h)) * DD + cg * 8;
        *(float4*)&orow[0] = make_float4(acc[i][0] * z, acc[i][1] * z, acc[i][2] * z, acc[i][3] * z);
        *(float4*)&orow[4] = make_float4(acc[i][4] * z, acc[i][5] * z, acc[i][6] * z, acc[i][7] * z);
    }
}

extern "C" void kernel_launch(void* const* d_in, const int* in_sizes, int n_in,
                              void* d_out, int out_size, void* d_ws, size_t ws_size,
                              hipStream_t stream) {
    const float* Q   = (const float*)d_in[0];
    const float* K   = (const float*)d_in[1];
    const float* V   = (const float*)d_in[2];
    const float* qm  = (const float*)d_in[3];
    const float* kvm = (const float*)d_in[4];
    float* out = (float*)d_out;

    // chunk count: (CH partials + 1 final) * 64 * 4160 floats must fit d_ws
    int CH = 32;
    while (CH > 1 && (size_t)(CH + 1) * NPAIR * KVSZ * sizeof(float) > ws_size) CH >>= 1;
    int SC = SK / CH;

    float* partial = (float*)d_ws;
    float* kvf = partial + (size_t)CH * NPAIR * KVSZ;

    kv_partial_kernel<<<dim3(NPAIR * CH), dim3(128), 0, stream>>>(K, V, kvm, partial, CH, SC);
    kv_reduce_kernel<<<dim3((NPAIR * KVSZ + 255) / 256), dim3(256), 0, stream>>>(partial, kvf, CH);
    attn_out_kernel<<<dim3(NPAIR * 64), dim3(128), 0, stream>>>(Q, qm, kvf, out);
}

// Round 4
// 84.551 us; speedup vs baseline: 1.2970x; 1.2970x over previous
//
#include <hip/hip_runtime.h>

#define NB 8
#define LQ 4096
#define SK 4096
#define NH 8
#define DD 64
#define NPAIR (NB*NH)        // 64 (n,h) pairs
#define KVSZ (DD*DD + DD)    // 4160: 64x64 KV + 64 Ksum

typedef short v8s __attribute__((ext_vector_type(8)));   // 8 bf16 (4 VGPR) MFMA operand
typedef float v4f __attribute__((ext_vector_type(4)));   // MFMA accumulator

union U8 { v8s s; unsigned int u[4]; };

__device__ __forceinline__ float fmap(float x) {
    return x > 0.f ? x + 1.f : __expf(x);   // elu+1
}
__device__ __forceinline__ unsigned short bf_hi(float x) {  // RNE fp32->bf16
    unsigned int u = __float_as_uint(x);
    return (unsigned short)((u + 0x7FFFu + ((u >> 16) & 1u)) >> 16);
}
__device__ __forceinline__ float bf_f(unsigned short b) {
    return __uint_as_float(((unsigned int)b) << 16);
}
// pack split: hi bf16 in low16, residual lo bf16 in high16
__device__ __forceinline__ unsigned int packpair(float x) {
    unsigned short h = bf_hi(x);
    unsigned short l = bf_hi(x - bf_f(h));
    return (unsigned int)h | ((unsigned int)l << 16);
}
// swizzled byte offset into a [32 s][64 d] array of 4B (hi|lo) pairs.
// reads (fixed j => s&7 const, varying lane&15 -> d, lane>>4 -> s>>3): 32 banks, 2-way.
// writes (b128 over 4 consecutive d): 8 distinct bank-quads, even coverage.
__device__ __forceinline__ int swz(int s, int d) {
    int b = (s << 8) | (d << 2);
    b ^= (s & 7) << 5;
    b ^= ((s >> 3) & 1) << 6;
    b ^= ((d >> 5) & 1) << 5;
    return b;
}

#define MFMA(A, B, C) __builtin_amdgcn_mfma_f32_16x16x32_bf16((A), (B), (C), 0, 0, 0)

// ---------------- Phase 1: partial KV = K^T V (+ ones-col => Ksum) via MFMA --------
// 2 waves/block, wave-private 32s x 64d tiles (no main-loop barriers).
// A[m=d][k=s] and B[k=s][n=v] fragments gathered elementwise from swizzled LDS.
__global__ __launch_bounds__(128) void kv_partial_kernel(
    const float* __restrict__ K, const float* __restrict__ V,
    const float* __restrict__ kvm, float* __restrict__ partial, int CH)
{
    int bx = blockIdx.x;
    int chunk = bx % CH;
    int pair  = bx / CH;
    int nb = pair >> 3, h = pair & 7;
    int w    = threadIdx.x >> 6;
    int lane = threadIdx.x & 63;
    int g    = lane >> 4;        // k-group
    int c16  = lane & 15;        // fragment row/col

    __shared__ unsigned int stage[2][2][32 * 64];  // [wave][K/V] swizzled pair arrays (32 KB)
    __shared__ float ksb[2][64];

    char* Ka = (char*)&stage[w][0][0];
    char* Va = (char*)&stage[w][1][0];

    v4f acc[4][4];   // [md][nn]
    v4f ksacc[4];    // [md] ones-column (Ksum)
    v4f z4 = {0.f, 0.f, 0.f, 0.f};
#pragma unroll
    for (int i = 0; i < 4; ++i) {
        ksacc[i] = z4;
#pragma unroll
        for (int j = 0; j < 4; ++j) acc[i][j] = z4;
    }

    U8 Bones;
#pragma unroll
    for (int p = 0; p < 4; ++p) Bones.u[p] = (c16 == 0) ? 0x3F803F80u : 0u;

    int SC = SK / CH;
    int tiles = SC >> 5;
    int srow = lane >> 1;           // staging: row 0..31
    int d0   = (lane & 1) << 5;     // staging: d half 0/32

    for (int it = w; it < tiles; it += 2) {
        int s0 = chunk * SC + (it << 5);
        // ---- stage 32x64 K,V as packed hi|lo pairs (fmap+mask applied) ----
        float m = kvm[nb * SK + s0 + srow];
        size_t gb = ((size_t)((nb * SK + s0 + srow) * NH + h)) * DD + d0;
#pragma unroll
        for (int c = 0; c < 8; ++c) {
            float4 kf = *(const float4*)(K + gb + 4 * c);
            uint4 kp;
            kp.x = packpair(fmap(kf.x) * m); kp.y = packpair(fmap(kf.y) * m);
            kp.z = packpair(fmap(kf.z) * m); kp.w = packpair(fmap(kf.w) * m);
            *(uint4*)(Ka + swz(srow, d0 + 4 * c)) = kp;
            float4 vf = *(const float4*)(V + gb + 4 * c);
            uint4 vp;
            vp.x = packpair(vf.x * m); vp.y = packpair(vf.y * m);
            vp.z = packpair(vf.z * m); vp.w = packpair(vf.w * m);
            *(uint4*)(Va + swz(srow, d0 + 4 * c)) = vp;
        }
        // wave-private LDS: compiler inserts lgkmcnt between write & read

        // ---- B fragments for all 4 n-tiles (hoisted) ----
        U8 Bh[4], Bl[4];
#pragma unroll
        for (int nn = 0; nn < 4; ++nn) {
            unsigned int br[8];
#pragma unroll
            for (int j = 0; j < 8; ++j)
                br[j] = *(const unsigned int*)(Va + swz(8 * g + j, 16 * nn + c16));
#pragma unroll
            for (int p = 0; p < 4; ++p) {
                Bh[nn].u[p] = (br[2*p] & 0xFFFFu) | (br[2*p+1] << 16);
                Bl[nn].u[p] = (br[2*p] >> 16)     | (br[2*p+1] & 0xFFFF0000u);
            }
        }
        // ---- A fragments per md + MFMA ----
#pragma unroll
        for (int md = 0; md < 4; ++md) {
            unsigned int ar[8];
#pragma unroll
            for (int j = 0; j < 8; ++j)
                ar[j] = *(const unsigned int*)(Ka + swz(8 * g + j, 16 * md + c16));
            U8 Ah, Al;
#pragma unroll
            for (int p = 0; p < 4; ++p) {
                Ah.u[p] = (ar[2*p] & 0xFFFFu) | (ar[2*p+1] << 16);
                Al.u[p] = (ar[2*p] >> 16)     | (ar[2*p+1] & 0xFFFF0000u);
            }
            ksacc[md] = MFMA(Ah.s, Bones.s, ksacc[md]);
            ksacc[md] = MFMA(Al.s, Bones.s, ksacc[md]);
#pragma unroll
            for (int nn = 0; nn < 4; ++nn) {
                acc[md][nn] = MFMA(Ah.s, Bh[nn].s, acc[md][nn]);
                acc[md][nn] = MFMA(Al.s, Bh[nn].s, acc[md][nn]);
                acc[md][nn] = MFMA(Ah.s, Bl[nn].s, acc[md][nn]);
            }
        }
    }

    // ---- epilogue: cross-wave reduce via LDS, write one partial per block ----
    float* dst = partial + ((size_t)chunk * NPAIR + pair) * KVSZ;
    float* scr = (float*)&stage[0][0][0];   // 16 KB scratch (2 waves x 2048 f32)
    int tid = threadIdx.x;

    if (c16 == 0) {
#pragma unroll
        for (int md = 0; md < 4; ++md)
#pragma unroll
            for (int jj = 0; jj < 4; ++jj)
                ksb[w][16 * md + 4 * g + jj] = ksacc[md][jj];
    }
    __syncthreads();   // frag reads done + ksb written
    if (tid < 64) dst[4096 + tid] = ksb[0][tid] + ksb[1][tid];

#pragma unroll
    for (int pass = 0; pass < 2; ++pass) {
#pragma unroll
        for (int md = 0; md < 4; ++md)
#pragma unroll
            for (int q = 0; q < 2; ++q) {
                int nn = pass * 2 + q;
#pragma unroll
                for (int jj = 0; jj < 4; ++jj)
                    scr[w * 2048 + (16 * md + 4 * g + jj) * 32 + q * 16 + c16] = acc[md][nn][jj];
            }
        __syncthreads();
        {
            int idx0 = tid * 16;
#pragma unroll
            for (int e = 0; e < 4; ++e) {
                int idx = idx0 + 4 * e;
                float4 x = *(float4*)&scr[idx];
                float4 y = *(float4*)&scr[2048 + idx];
                float4 s4 = make_float4(x.x + y.x, x.y + y.y, x.z + y.z, x.w + y.w);
                *(float4*)&dst[(idx >> 5) * 64 + pass * 32 + (idx & 31)] = s4;
            }
        }
        __syncthreads();
    }
}

// ---------------- Phase 1b: reduce partials over chunks -----------------
__global__ __launch_bounds__(256) void kv_reduce_kernel(
    const float* __restrict__ partial, float* __restrict__ kvf, int CH)
{
    int i = blockIdx.x * 256 + threadIdx.x;
    if (i >= NPAIR * KVSZ) return;
    float s = 0.f;
    for (int c = 0; c < CH; ++c) s += partial[(size_t)c * NPAIR * KVSZ + i];
    kvf[i] = s;
}

// ---------------- Phase 2: out = (q.KV)/(q.Ksum + eps) via MFMA, no LDS --------
// B (KV) fragments preloaded to VGPR once per block from L2-resident kvf.
// A (Q) loaded straight from global in fragment layout (row = lane&15).
__global__ __launch_bounds__(256) void attn_out_kernel(
    const float* __restrict__ Q, const float* __restrict__ qm,
    const float* __restrict__ kvf, float* __restrict__ out)
{
    int bx = blockIdx.x;
    int pair = bx >> 4;            // 16 consecutive blocks share a pair (L2)
    int rb   = bx & 15;            // 256-row group
    int nb = pair >> 3, h = pair & 7;
    int lane = threadIdx.x & 63;
    int w    = threadIdx.x >> 6;
    int g    = lane >> 4;
    int c16  = lane & 15;

    const float* kvp = kvf + (size_t)pair * KVSZ;

    // ---- preload B fragments (hi only for KV; hi+lo for Ksum column) ----
    U8 Bh[2][4], Bkh[2], Bkl[2];
#pragma unroll
    for (int ks = 0; ks < 2; ++ks) {
#pragma unroll
        for (int nn = 0; nn < 4; ++nn) {
            unsigned short hs[8];
#pragma unroll
            for (int j = 0; j < 8; ++j)
                hs[j] = bf_hi(kvp[(32 * ks + 8 * g + j) * 64 + 16 * nn + c16]);
#pragma unroll
            for (int p = 0; p < 4; ++p)
                Bh[ks][nn].u[p] = (unsigned int)hs[2*p] | ((unsigned int)hs[2*p+1] << 16);
        }
        unsigned int kh[8], kl[8];
#pragma unroll
        for (int j = 0; j < 8; ++j) {
            float x = kvp[4096 + 32 * ks + 8 * g + j];
            unsigned short hh = bf_hi(x);
            kh[j] = hh;
            kl[j] = bf_hi(x - bf_f(hh));
        }
#pragma unroll
        for (int p = 0; p < 4; ++p) {
            Bkh[ks].u[p] = (c16 == 0) ? (kh[2*p] | (kh[2*p+1] << 16)) : 0u;
            Bkl[ks].u[p] = (c16 == 0) ? (kl[2*p] | (kl[2*p+1] << 16)) : 0u;
        }
    }

    v4f z4 = {0.f, 0.f, 0.f, 0.f};
#pragma unroll
    for (int it = 0; it < 4; ++it) {
        int row0 = rb * 256 + (w + 4 * it) * 16;
        int row  = row0 + c16;
        float qmv = qm[nb * LQ + row];
        const float* qrow = Q + ((size_t)((nb * LQ + row) * NH + h)) * DD;

        U8 Ah[2], Al[2];
#pragma unroll
        for (int ks = 0; ks < 2; ++ks) {
            float4 q0 = *(const float4*)(qrow + 8 * g + 32 * ks);
            float4 q1 = *(const float4*)(qrow + 8 * g + 32 * ks + 4);
            float qv[8] = {q0.x, q0.y, q0.z, q0.w, q1.x, q1.y, q1.z, q1.w};
            unsigned int pp[8];
#pragma unroll
            for (int j = 0; j < 8; ++j) pp[j] = packpair(fmap(qv[j]) * qmv);
#pragma unroll
            for (int p = 0; p < 4; ++p) {
                Ah[ks].u[p] = (pp[2*p] & 0xFFFFu) | (pp[2*p+1] << 16);
                Al[ks].u[p] = (pp[2*p] >> 16)     | (pp[2*p+1] & 0xFFFF0000u);
            }
        }

        v4f a0 = z4, a1 = z4, a2 = z4, a3 = z4, a4 = z4;
#pragma unroll
        for (int ks = 0; ks < 2; ++ks) {
            a0 = MFMA(Ah[ks].s, Bh[ks][0].s, a0);
            a1 = MFMA(Ah[ks].s, Bh[ks][1].s, a1);
            a2 = MFMA(Ah[ks].s, Bh[ks][2].s, a2);
            a3 = MFMA(Ah[ks].s, Bh[ks][3].s, a3);
            a0 = MFMA(Al[ks].s, Bh[ks][0].s, a0);
            a1 = MFMA(Al[ks].s, Bh[ks][1].s, a1);
            a2 = MFMA(Al[ks].s, Bh[ks][2].s, a2);
            a3 = MFMA(Al[ks].s, Bh[ks][3].s, a3);
            a4 = MFMA(Ah[ks].s, Bkh[ks].s, a4);
            a4 = MFMA(Al[ks].s, Bkh[ks].s, a4);
            a4 = MFMA(Ah[ks].s, Bkl[ks].s, a4);
        }

        // denominator lives in col 0 of the a4 tile -> broadcast from group leader
        int src = lane & 48;
#pragma unroll
        for (int jj = 0; jj < 4; ++jj) {
            float den = __shfl(a4[jj], src);
            float z = 1.f / (den + 1e-6f);
            size_t ob = ((size_t)((nb * LQ + row0 + 4 * g + jj) * NH + h)) * DD + c16;
            out[ob]      = a0[jj] * z;
            out[ob + 16] = a1[jj] * z;
            out[ob + 32] = a2[jj] * z;
            out[ob + 48] = a3[jj] * z;
        }
    }
}

extern "C" void kernel_launch(void* const* d_in, const int* in_sizes, int n_in,
                              void* d_out, int out_size, void* d_ws, size_t ws_size,
                              hipStream_t stream) {
    const float* Q   = (const float*)d_in[0];
    const float* K   = (const float*)d_in[1];
    const float* V   = (const float*)d_in[2];
    const float* qm  = (const float*)d_in[3];
    const float* kvm = (const float*)d_in[4];
    float* out = (float*)d_out;

    int CH = 16;   // (CH+1)*64*4160*4B = 17.7 MB workspace (fits per round-1 run)
    while (CH > 1 && (size_t)(CH + 1) * NPAIR * KVSZ * sizeof(float) > ws_size) CH >>= 1;

    float* partial = (float*)d_ws;
    float* kvf = partial + (size_t)CH * NPAIR * KVSZ;

    kv_partial_kernel<<<dim3(NPAIR * CH), dim3(128), 0, stream>>>(K, V, kvm, partial, CH);
    kv_reduce_kernel<<<dim3((NPAIR * KVSZ + 255) / 256), dim3(256), 0, stream>>>(partial, kvf, CH);
    attn_out_kernel<<<dim3(NPAIR * 16), dim3(256), 0, stream>>>(Q, qm, kvf, out);
}